// Round 3
// baseline (222.773 us; speedup 1.0000x reference)
//
#include <hip/hip_runtime.h>
#include <hip/hip_fp16.h>

// SpatialTransform: fused meshgrid + flow displacement + bilinear grid_sample
// (align_corners=True, padding_mode='border'). B=16, C=4, H=W=512, fp32.
// d_out = [ sample_grid (B*H*W*2 floats) | warped (B*C*H*W floats) ]
//
// R6 (from R5 @ 219.8us, pass2 ~64us):
//  - R5 counters: WRITE_SIZE 130MB = ideal 96MB + 32MB grid amplification.
//    Cause: grid stored as 2x16B per thread at 32B lane stride (half-line
//    per instruction) with nt (no L2 merge) -> 2x write traffic on grid.
//    FIX: grid stores are now plain (L2 write-allocate merges half-lines;
//    R3 with merged stores showed exactly-ideal WRITE_SIZE). Warped stores
//    stay nt (lane-contiguous full lines, no amplification).
//  - Pass 1 had the same half-line store pattern (copyA/copyB 16B @ 32B
//    stride + divergent edge stores) -> possible L2 partial-line RMW fills.
//    FIX: stage both copies in LDS (16KB/block), then write 4 fully
//    lane-contiguous dwordx4 stores per thread after one barrier.
//  Kept from R4/R5: 4 px/thread (8 gathers in flight), nt loads (img/flow),
//  nt warped stores, XCD slab swizzle (pass2 reversed), dual fp16 copies.

#define HW    512
#define BATCH 16
#define CH     4
#define HWHW  (HW * HW)

typedef float fvec4 __attribute__((ext_vector_type(4)));

union H4 { uint2 u; __half2 h[2]; };   // one pixel: 4 channels fp16
union Q  { uint4 u; __half2 h[4]; };   // one slot: 2 pixels x 4 channels fp16

// ---------------------------------------------------------------------------
// Pass 1: [B,C,H,W] fp32 -> two fp16 HWC copies. 4 pixels/thread, 2 rows/block.
// copyA slot p = pixel p. copyB slot p (row-local) = pixel p+1 (slot 511 = px 511).
// Staged through LDS so all global stores are lane-contiguous full lines.
__global__ __launch_bounds__(256) void transpose_fp16_dual(
    const fvec4* __restrict__ img4,
    uint2* __restrict__ copyA,
    uint2* __restrict__ copyB)
{
    // 4096 blocks; xcd = j&7 owns contiguous 256-row slabs (forward order).
    const int j    = blockIdx.x;
    const int xcd  = j & 7;
    const int i    = j >> 3;                        // 0..511
    const int slab = ((i >> 7) << 3) | xcd;         // 0..31
    const int rp   = (slab << 7) | (i & 127);       // row-pair 0..4095
    const int rb   = (int)threadIdx.x >> 7;         // row within block (0/1)
    const int r    = (rp << 1) | rb;                // global row 0..8191
    const int lane = (int)threadIdx.x & 127;
    const int b    = r >> 9;
    const int y    = r & (HW - 1);
    const int x    = lane << 2;                     // 0,4,...,508

    const int q = (y * HW + x) >> 2;                // quad index within plane

    const fvec4* ib = img4 + (size_t)b * CH * (HWHW / 4) + q;
    const fvec4 c0 = __builtin_nontemporal_load(ib + 0 * (HWHW / 4));
    const fvec4 c1 = __builtin_nontemporal_load(ib + 1 * (HWHW / 4));
    const fvec4 c2 = __builtin_nontemporal_load(ib + 2 * (HWHW / 4));
    const fvec4 c3 = __builtin_nontemporal_load(ib + 3 * (HWHW / 4));

    H4 v0, v1, v2, v3;                              // pixels x..x+3 of row r
    v0.h[0] = __floats2half2_rn(c0.x, c1.x); v0.h[1] = __floats2half2_rn(c2.x, c3.x);
    v1.h[0] = __floats2half2_rn(c0.y, c1.y); v1.h[1] = __floats2half2_rn(c2.y, c3.y);
    v2.h[0] = __floats2half2_rn(c0.z, c1.z); v2.h[1] = __floats2half2_rn(c2.z, c3.z);
    v3.h[0] = __floats2half2_rn(c0.w, c1.w); v3.h[1] = __floats2half2_rn(c2.w, c3.w);

    // Stage in LDS: two rows of each copy, row-local layout.
    __shared__ uint2 As[2 * HW];
    __shared__ uint2 Bs[2 * HW];
    const int sb = (rb << 9) + x;                   // row-local slot base
    As[sb + 0] = v0.u;  As[sb + 1] = v1.u;
    As[sb + 2] = v2.u;  As[sb + 3] = v3.u;
    // B[s] = pixel s+1 within the row; slot 511 replicates pixel 511.
    if (x != 0)       Bs[sb - 1] = v0.u;
    Bs[sb + 0] = v1.u;  Bs[sb + 1] = v2.u;  Bs[sb + 2] = v3.u;
    if (x == HW - 4)  Bs[sb + 3] = v3.u;

    __syncthreads();

    // Write out: 4 lane-contiguous dwordx4 stores per thread (full lines).
    const int t  = (int)threadIdx.x;
    const int r0 = rp << 1;                         // first row of block
    const uint4* As4 = (const uint4*)As;            // 512 uint4
    const uint4* Bs4 = (const uint4*)Bs;
    uint4* dA = (uint4*)copyA + (size_t)r0 * (HW / 2);
    uint4* dB = (uint4*)copyB + (size_t)r0 * (HW / 2);
    dA[t]       = As4[t];
    dA[t + 256] = As4[t + 256];
    dB[t]       = Bs4[t];
    dB[t + 256] = Bs4[t + 256];
}

// ---------------------------------------------------------------------------
// Bilinear addressing into the dual-copy fp16 image.
__device__ __forceinline__ void addr2(const uint4* __restrict__ A,
                                      const uint4* __restrict__ B,
                                      float gx, float gy,
                                      const uint4** p0, const uint4** p1,
                                      float* wx, float* wy)
{
    float xs = fminf(fmaxf((gx + 1.0f) * 0.5f * 511.0f, 0.0f), 511.0f);
    float ys = fminf(fmaxf((gy + 1.0f) * 0.5f * 511.0f, 0.0f), 511.0f);
    const float x0f = floorf(xs);
    const float y0f = floorf(ys);
    *wx = xs - x0f;
    *wy = ys - y0f;
    const int x0 = (int)x0f;
    const int y0 = (int)y0f;
    const int y1 = min(y0 + 1, HW - 1);
    const uint4* base = (x0 & 1) ? B : A;
    const int slot = x0 >> 1;
    *p0 = base + y0 * (HW / 2) + slot;
    *p1 = base + y1 * (HW / 2) + slot;
}

__device__ __forceinline__ float4 blend(Q r0, Q r1, float wx, float wy)
{
    const float w00 = (1.0f - wx) * (1.0f - wy);
    const float w01 = wx * (1.0f - wy);
    const float w10 = (1.0f - wx) * wy;
    const float w11 = wx * wy;
    float4 o;
    o.x = w00 * __low2float (r0.h[0]) + w01 * __low2float (r0.h[2])
        + w10 * __low2float (r1.h[0]) + w11 * __low2float (r1.h[2]);
    o.y = w00 * __high2float(r0.h[0]) + w01 * __high2float(r0.h[2])
        + w10 * __high2float(r1.h[0]) + w11 * __high2float(r1.h[2]);
    o.z = w00 * __low2float (r0.h[1]) + w01 * __low2float (r0.h[3])
        + w10 * __low2float (r1.h[1]) + w11 * __low2float (r1.h[3]);
    o.w = w00 * __high2float(r0.h[1]) + w01 * __high2float(r0.h[3])
        + w10 * __high2float(r1.h[1]) + w11 * __high2float(r1.h[3]);
    return o;
}

// Pass 2: 4 px/thread, 2 rows/block, slab-swizzled to XCDs in REVERSE order
// (starts where pass 1 finished -> L2-hot). 8 gather loads in flight.
__global__ __launch_bounds__(256) void spatial_transform_fp16(
    const uint4* __restrict__ copyA,
    const uint4* __restrict__ copyB,
    const fvec4* __restrict__ flow4, // [B*H*W/2]: (fh0,fw0,fh1,fw1)
    fvec4* __restrict__ grid4,       // [B*H*W/2]: (gx0,gy0,gx1,gy1)
    float* __restrict__ warped)      // [B,C,H,W]
{
    const int j    = blockIdx.x;                    // 0..4095
    const int xcd  = j & 7;
    const int i    = (j >> 3) ^ 511;                // REVERSED intra-XCD order
    const int slab = ((i >> 7) << 3) | xcd;         // 0..31
    const int rp   = (slab << 7) | (i & 127);       // row-pair 0..4095
    const int r    = (rp << 1) | ((int)threadIdx.x >> 7);  // global row
    const int lane = (int)threadIdx.x & 127;
    const int b    = r >> 9;
    const int y    = r & (HW - 1);
    const int x    = lane << 2;

    const int p = r * HW + x;                       // global pixel index
    const fvec4 f01 = __builtin_nontemporal_load(flow4 + (p >> 1) + 0);
    const fvec4 f23 = __builtin_nontemporal_load(flow4 + (p >> 1) + 1);

    const float scale = 2.0f / 511.0f;
    const float by = fmaf((float)y, scale, -1.0f);
    const float gy0 = by + f01.x;
    const float gx0 = fmaf((float)(x + 0), scale, -1.0f) + f01.y;
    const float gy1 = by + f01.z;
    const float gx1 = fmaf((float)(x + 1), scale, -1.0f) + f01.w;
    const float gy2 = by + f23.x;
    const float gx2 = fmaf((float)(x + 2), scale, -1.0f) + f23.y;
    const float gy3 = by + f23.z;
    const float gx3 = fmaf((float)(x + 3), scale, -1.0f) + f23.w;

    const uint4* A  = copyA + (size_t)b * (HW * (HW / 2));
    const uint4* Bc = copyB + (size_t)b * (HW * (HW / 2));

    // Phase A: all addresses
    const uint4 *p00, *p01, *p10, *p11, *p20, *p21, *p30, *p31;
    float wx0, wy0, wx1, wy1, wx2, wy2, wx3, wy3;
    addr2(A, Bc, gx0, gy0, &p00, &p01, &wx0, &wy0);
    addr2(A, Bc, gx1, gy1, &p10, &p11, &wx1, &wy1);
    addr2(A, Bc, gx2, gy2, &p20, &p21, &wx2, &wy2);
    addr2(A, Bc, gx3, gy3, &p30, &p31, &wx3, &wy3);

    // Phase B: 8 independent gathers in flight
    Q q00, q01, q10, q11, q20, q21, q30, q31;
    q00.u = *p00; q01.u = *p01;
    q10.u = *p10; q11.u = *p11;
    q20.u = *p20; q21.u = *p21;
    q30.u = *p30; q31.u = *p31;

    // grid store overlaps the gather latency. PLAIN stores (no nt): two 16B
    // stores at 32B lane stride are half-line each; L2 write-allocate merges
    // them into full lines (nt here cost +32MB HBM writes in R5).
    fvec4 g01; g01.x = gx0; g01.y = gy0; g01.z = gx1; g01.w = gy1;
    fvec4 g23; g23.x = gx2; g23.y = gy2; g23.z = gx3; g23.w = gy3;
    grid4[(p >> 1) + 0] = g01;
    grid4[(p >> 1) + 1] = g23;

    // Phase C: blend + transposed channel stores (lane-contiguous -> keep nt)
    const float4 s0 = blend(q00, q01, wx0, wy0);
    const float4 s1 = blend(q10, q11, wx1, wy1);
    const float4 s2 = blend(q20, q21, wx2, wy2);
    const float4 s3 = blend(q30, q31, wx3, wy3);

    fvec4* wb = (fvec4*)(warped + (size_t)b * CH * HWHW + y * HW + x);
    fvec4 o0; o0.x = s0.x; o0.y = s1.x; o0.z = s2.x; o0.w = s3.x;
    fvec4 o1; o1.x = s0.y; o1.y = s1.y; o1.z = s2.y; o1.w = s3.y;
    fvec4 o2; o2.x = s0.z; o2.y = s1.z; o2.z = s2.z; o2.w = s3.z;
    fvec4 o3; o3.x = s0.w; o3.y = s1.w; o3.z = s2.w; o3.w = s3.w;
    __builtin_nontemporal_store(o0, wb + 0 * (HWHW / 4));
    __builtin_nontemporal_store(o1, wb + 1 * (HWHW / 4));
    __builtin_nontemporal_store(o2, wb + 2 * (HWHW / 4));
    __builtin_nontemporal_store(o3, wb + 3 * (HWHW / 4));
}

// ---------------------------------------------------------------------------
// Fallback (R0 path) if workspace is too small.
__global__ __launch_bounds__(256) void spatial_transform_chw(
    const float*  __restrict__ img,
    const float2* __restrict__ flow,
    float2*       __restrict__ grid_out,
    float*        __restrict__ warped)
{
    const int tid = blockIdx.x * blockDim.x + threadIdx.x;
    const int x = tid & (HW - 1);
    const int y = (tid >> 9) & (HW - 1);
    const int b = tid >> 18;

    const float2 f = flow[tid];
    const float scale = 2.0f / 511.0f;
    const float gy = fmaf((float)y, scale, -1.0f) + f.x;
    const float gx = fmaf((float)x, scale, -1.0f) + f.y;
    grid_out[tid] = make_float2(gx, gy);

    float xs = fminf(fmaxf((gx + 1.0f) * 0.5f * 511.0f, 0.0f), 511.0f);
    float ys = fminf(fmaxf((gy + 1.0f) * 0.5f * 511.0f, 0.0f), 511.0f);
    const float x0f = floorf(xs), y0f = floorf(ys);
    const float wx = xs - x0f, wy = ys - y0f;
    const int x0 = (int)x0f, y0 = (int)y0f;
    const int x1 = min(x0 + 1, HW - 1), y1 = min(y0 + 1, HW - 1);
    const float w00 = (1.0f - wx) * (1.0f - wy), w01 = wx * (1.0f - wy);
    const float w10 = (1.0f - wx) * wy,          w11 = wx * wy;
    const int o00 = y0 * HW + x0, o01 = y0 * HW + x1;
    const int o10 = y1 * HW + x0, o11 = y1 * HW + x1;
    const float* ib = img    + (size_t)b * CH * HWHW;
    float*       wb = warped + (size_t)b * CH * HWHW + y * HW + x;
#pragma unroll
    for (int c = 0; c < CH; ++c) {
        const float* pc = ib + c * HWHW;
        wb[c * HWHW] = pc[o00] * w00 + pc[o01] * w01 + pc[o10] * w10 + pc[o11] * w11;
    }
}

extern "C" void kernel_launch(void* const* d_in, const int* in_sizes, int n_in,
                              void* d_out, int out_size, void* d_ws, size_t ws_size,
                              hipStream_t stream) {
    const float* img  = (const float*)d_in[0];
    const void*  flow = d_in[1];

    float* grid_out = (float*)d_out;                                  // B*H*W*2 floats
    float* warped   = (float*)d_out + (size_t)BATCH * HWHW * 2;       // B*C*H*W floats

    const int n_px = BATCH * HWHW;                       // 4,194,304 pixels
    const size_t copy_bytes = (size_t)n_px * 8;          // 32 MiB per fp16 copy
    const size_t need = 2 * copy_bytes;                  // 64 MiB

    if (ws_size >= need) {
        uint2* copyA = (uint2*)d_ws;
        uint2* copyB = (uint2*)((char*)d_ws + copy_bytes);
        transpose_fp16_dual<<<(n_px / 4) / 256, 256, 0, stream>>>(
            (const fvec4*)img, copyA, copyB);
        spatial_transform_fp16<<<(n_px / 4) / 256, 256, 0, stream>>>(
            (const uint4*)copyA, (const uint4*)copyB,
            (const fvec4*)flow, (fvec4*)grid_out, warped);
    } else {
        spatial_transform_chw<<<n_px / 256, 256, 0, stream>>>(
            img, (const float2*)flow, (float2*)grid_out, warped);
    }
}

// Round 4
// 215.508 us; speedup vs baseline: 1.0337x; 1.0337x over previous
//
#include <hip/hip_runtime.h>
#include <hip/hip_fp16.h>

// SpatialTransform: fused meshgrid + flow displacement + bilinear grid_sample
// (align_corners=True, padding_mode='border'). B=16, C=4, H=W=512, fp32.
// d_out = [ sample_grid (B*H*W*2 floats) | warped (B*C*H*W floats) ]
//
// R7 (from R6 @ 222.8us, pass2 68.6us):
//  Diagnosis: pass2 is L1-miss-throughput bound. Flow noise sigma~25px ->
//  every gather lane hits a distinct 64B line (L1 hit ~0); ~537MB of line
//  traffic at ~1 miss/5cy/CU = 68us. Lever = distinct lines per sample.
//  1. Y-PAIRED copies: E[yp][x] (16B) = px (x,2yp)+(x,2yp+1); O[yp][x] =
//     rows (2yp+1, 2yp+2). A bilinear sample = 2 ADJACENT 16B entries
//     (x0,x0+1) -> same 64B line 75% -> lines/sample 2.0 -> 1.25.
//     Same 64MiB ws, same load count, bit-identical numerics.
//  2. nt grid stores RESTORED but lane-contiguous (thread owns pixel-pairs
//     l and l+128, not 2t,2t+1): R5 showed nt-grid is worth ~4.6us (keeps
//     copies in L2) but cost +32MB when half-line; now full-line, no cost.
//     R6 proved plain partial-line stores merge in L2 w/o fill (FETCH flat),
//     used for pass-1 O halves.
//  Kept: 4px/thread (8 gathers in flight), nt img/flow loads, nt warped
//  stores, XCD slab swizzle (pass1 forward, pass2 reversed), LDS-staged
//  pass-1 stores.

#define HW    512
#define BATCH 16
#define CH     4
#define HWHW  (HW * HW)

typedef float fvec4 __attribute__((ext_vector_type(4)));
typedef float fvec2 __attribute__((ext_vector_type(2)));

union H4 { uint2 u; __half2 h[2]; };   // one pixel: 4 channels fp16
union Q  { uint4 u; __half2 h[4]; };   // one entry: 2 pixels x 4 channels fp16

// ---------------------------------------------------------------------------
// Pass 1: [B,C,H,W] fp32 -> two y-paired fp16 HWC copies.
// E[rp][x] = {px(x,2rp), px(x,2rp+1)}; O[yp][x] = {px(x,2yp+1), px(x,2yp+2)}
// (top: O[255].hi = row 511). Block = one row-pair (2 rows), LDS-staged so
// E stores are full 16B lane-contiguous; O written as 8B halves (L2 merges).
__global__ __launch_bounds__(256) void transpose_fp16_dual(
    const fvec4* __restrict__ img4,
    uint4* __restrict__ E,
    uint4* __restrict__ O)
{
    // 4096 blocks; xcd = j&7 owns contiguous slabs (forward order).
    const int j    = blockIdx.x;
    const int xcd  = j & 7;
    const int i    = j >> 3;                        // 0..511
    const int slab = ((i >> 7) << 3) | xcd;         // 0..31
    const int rp   = (slab << 7) | (i & 127);       // global row-pair 0..4095
    const int rb   = (int)threadIdx.x >> 7;         // row within pair (0/1)
    const int r    = (rp << 1) | rb;                // global row 0..8191
    const int lane = (int)threadIdx.x & 127;
    const int b    = r >> 9;
    const int y    = r & (HW - 1);
    const int x    = lane << 2;                     // 0,4,...,508

    const int q = (y * HW + x) >> 2;                // quad index within plane
    const fvec4* ib = img4 + (size_t)b * CH * (HWHW / 4) + q;
    const fvec4 c0 = __builtin_nontemporal_load(ib + 0 * (HWHW / 4));
    const fvec4 c1 = __builtin_nontemporal_load(ib + 1 * (HWHW / 4));
    const fvec4 c2 = __builtin_nontemporal_load(ib + 2 * (HWHW / 4));
    const fvec4 c3 = __builtin_nontemporal_load(ib + 3 * (HWHW / 4));

    H4 v0, v1, v2, v3;                              // pixels x..x+3 of row r
    v0.h[0] = __floats2half2_rn(c0.x, c1.x); v0.h[1] = __floats2half2_rn(c2.x, c3.x);
    v1.h[0] = __floats2half2_rn(c0.y, c1.y); v1.h[1] = __floats2half2_rn(c2.y, c3.y);
    v2.h[0] = __floats2half2_rn(c0.z, c1.z); v2.h[1] = __floats2half2_rn(c2.z, c3.z);
    v3.h[0] = __floats2half2_rn(c0.w, c1.w); v3.h[1] = __floats2half2_rn(c2.w, c3.w);

    // Stage in LDS interleaved by row: S[x][rb]; (uint4*)S[x] = {row0,row1}.
    __shared__ uint2 S[HW][2];
    S[x + 0][rb] = v0.u;
    S[x + 1][rb] = v1.u;
    S[x + 2][rb] = v2.u;
    S[x + 3][rb] = v3.u;
    __syncthreads();

    const int t   = (int)threadIdx.x;
    const int rpl = rp & 255;                       // row-pair within image
    const uint4* S4 = (const uint4*)S;              // S4[x] = y-paired entry

    // E: full 16B lane-contiguous stores (plain: want them resident in L2).
    uint4* Ed = E + ((size_t)rp << 9);
    Ed[t]       = S4[t];
    Ed[t + 256] = S4[t + 256];

    // O lo-half (row 2rp+1): 8B stores at 16B stride; hi comes from block
    // rp+1 in the same slab/XCD -> L2 merges (R6: no fill, no amplification).
    uint2* Olo = (uint2*)(O + ((size_t)rp << 9));
    Olo[2 * t]         = S[t][1];
    Olo[2 * (t + 256)] = S[t + 256][1];
    // O hi-half for yp=rp-1 (row 2rp):
    if (rpl != 0) {
        uint2* Ohi = (uint2*)(O + ((size_t)(rp - 1) << 9));
        Ohi[2 * t + 1]         = S[t][0];
        Ohi[2 * (t + 256) + 1] = S[t + 256][0];
    }
    if (rpl == 255) {                               // clamp: row 512 -> 511
        Olo[2 * t + 1]         = S[t][1];
        Olo[2 * (t + 256) + 1] = S[t + 256][1];
    }
}

// ---------------------------------------------------------------------------
// Bilinear addressing into the y-paired copies.
__device__ __forceinline__ void addrEO(const uint4* __restrict__ E,
                                       const uint4* __restrict__ O,
                                       float gx, float gy,
                                       const uint4** p0, int* dx,
                                       float* wx, float* wy)
{
    float xs = fminf(fmaxf((gx + 1.0f) * 0.5f * 511.0f, 0.0f), 511.0f);
    float ys = fminf(fmaxf((gy + 1.0f) * 0.5f * 511.0f, 0.0f), 511.0f);
    const float x0f = floorf(xs);
    const float y0f = floorf(ys);
    *wx = xs - x0f;
    *wy = ys - y0f;
    const int x0 = (int)x0f;
    const int y0 = (int)y0f;
    const uint4* base = (y0 & 1) ? O : E;
    *p0 = base + (((size_t)(y0 >> 1)) << 9) + x0;
    *dx = (x0 < HW - 1) ? 1 : 0;                    // border clamp in x
}

// c0 = column x0: {v00 (h[0..1]), v10 (h[2..3])}; c1 = column x1: {v01, v11}.
// Accumulation order identical to R3-R6 (bitwise-stable result).
__device__ __forceinline__ float4 blendEO(Q c0, Q c1, float wx, float wy)
{
    const float w00 = (1.0f - wx) * (1.0f - wy);
    const float w01 = wx * (1.0f - wy);
    const float w10 = (1.0f - wx) * wy;
    const float w11 = wx * wy;
    float4 o;
    o.x = w00 * __low2float (c0.h[0]) + w01 * __low2float (c1.h[0])
        + w10 * __low2float (c0.h[2]) + w11 * __low2float (c1.h[2]);
    o.y = w00 * __high2float(c0.h[0]) + w01 * __high2float(c1.h[0])
        + w10 * __high2float(c0.h[2]) + w11 * __high2float(c1.h[2]);
    o.z = w00 * __low2float (c0.h[1]) + w01 * __low2float (c1.h[1])
        + w10 * __low2float (c0.h[3]) + w11 * __low2float (c1.h[3]);
    o.w = w00 * __high2float(c0.h[1]) + w01 * __high2float(c1.h[1])
        + w10 * __high2float(c0.h[3]) + w11 * __high2float(c1.h[3]);
    return o;
}

// Pass 2: 2 rows/block, thread owns pixel-pairs l and l+128 of its row
// (every global load/store instruction lane-contiguous -> nt safe).
// Slab-swizzled to XCDs in REVERSE order (starts where pass 1 finished).
__global__ __launch_bounds__(256) void spatial_transform_fp16(
    const uint4* __restrict__ E,
    const uint4* __restrict__ O,
    const fvec4* __restrict__ flow4, // [B*H*W/2]: (fh0,fw0,fh1,fw1)
    fvec4* __restrict__ grid4,       // [B*H*W/2]: (gx0,gy0,gx1,gy1)
    float* __restrict__ warped)      // [B,C,H,W]
{
    const int j    = blockIdx.x;                    // 0..4095
    const int xcd  = j & 7;
    const int i    = (j >> 3) ^ 511;                // REVERSED intra-XCD order
    const int slab = ((i >> 7) << 3) | xcd;         // 0..31
    const int rp   = (slab << 7) | (i & 127);       // row-pair 0..4095
    const int r    = (rp << 1) | ((int)threadIdx.x >> 7);  // global row
    const int l    = (int)threadIdx.x & 127;
    const int b    = r >> 9;
    const int y    = r & (HW - 1);

    const int rowq = r << 8;                        // first pair-idx of row
    const fvec4 fA = __builtin_nontemporal_load(flow4 + rowq + l);
    const fvec4 fB = __builtin_nontemporal_load(flow4 + rowq + l + 128);

    const float scale = 2.0f / 511.0f;
    const float by = fmaf((float)y, scale, -1.0f);
    const int  xA = l << 1;                         // pixels xA, xA+1
    const int  xB = xA + 256;                       // pixels xB, xB+1
    const float gyA0 = by + fA.x;
    const float gxA0 = fmaf((float)(xA + 0), scale, -1.0f) + fA.y;
    const float gyA1 = by + fA.z;
    const float gxA1 = fmaf((float)(xA + 1), scale, -1.0f) + fA.w;
    const float gyB0 = by + fB.x;
    const float gxB0 = fmaf((float)(xB + 0), scale, -1.0f) + fB.y;
    const float gyB1 = by + fB.z;
    const float gxB1 = fmaf((float)(xB + 1), scale, -1.0f) + fB.w;

    const uint4* Eb = E + ((size_t)b << 17);        // 256*512 entries/image
    const uint4* Ob = O + ((size_t)b << 17);

    // Phase A: all addresses
    const uint4 *pA0, *pA1, *pB0, *pB1;
    int dA0, dA1, dB0, dB1;
    float wxA0, wyA0, wxA1, wyA1, wxB0, wyB0, wxB1, wyB1;
    addrEO(Eb, Ob, gxA0, gyA0, &pA0, &dA0, &wxA0, &wyA0);
    addrEO(Eb, Ob, gxA1, gyA1, &pA1, &dA1, &wxA1, &wyA1);
    addrEO(Eb, Ob, gxB0, gyB0, &pB0, &dB0, &wxB0, &wyB0);
    addrEO(Eb, Ob, gxB1, gyB1, &pB1, &dB1, &wxB1, &wyB1);

    // Phase B: 8 independent gathers in flight (pairs mostly share lines)
    Q a00, a01, a10, a11, b00, b01, b10, b11;
    a00.u = pA0[0]; a01.u = pA0[dA0];
    a10.u = pA1[0]; a11.u = pA1[dA1];
    b00.u = pB0[0]; b01.u = pB0[dB0];
    b10.u = pB1[0]; b11.u = pB1[dB1];

    // grid: nt + lane-contiguous (16B/lane, no amplification, no L2 pollution)
    fvec4 gA; gA.x = gxA0; gA.y = gyA0; gA.z = gxA1; gA.w = gyA1;
    fvec4 gB; gB.x = gxB0; gB.y = gyB0; gB.z = gxB1; gB.w = gyB1;
    __builtin_nontemporal_store(gA, grid4 + rowq + l);
    __builtin_nontemporal_store(gB, grid4 + rowq + l + 128);

    // Phase C: blend + transposed channel stores (8B/lane, lane-contiguous)
    const float4 s0 = blendEO(a00, a01, wxA0, wyA0);   // pixel xA
    const float4 s1 = blendEO(a10, a11, wxA1, wyA1);   // pixel xA+1
    const float4 s2 = blendEO(b00, b01, wxB0, wyB0);   // pixel xB
    const float4 s3 = blendEO(b10, b11, wxB1, wyB1);   // pixel xB+1

    fvec2* w2 = (fvec2*)(warped + (size_t)b * CH * HWHW + y * HW);
    fvec2 o0a; o0a.x = s0.x; o0a.y = s1.x;
    fvec2 o0b; o0b.x = s2.x; o0b.y = s3.x;
    fvec2 o1a; o1a.x = s0.y; o1a.y = s1.y;
    fvec2 o1b; o1b.x = s2.y; o1b.y = s3.y;
    fvec2 o2a; o2a.x = s0.z; o2a.y = s1.z;
    fvec2 o2b; o2b.x = s2.z; o2b.y = s3.z;
    fvec2 o3a; o3a.x = s0.w; o3a.y = s1.w;
    fvec2 o3b; o3b.x = s2.w; o3b.y = s3.w;
    __builtin_nontemporal_store(o0a, w2 + 0 * (HWHW / 2) + l);
    __builtin_nontemporal_store(o0b, w2 + 0 * (HWHW / 2) + l + 128);
    __builtin_nontemporal_store(o1a, w2 + 1 * (HWHW / 2) + l);
    __builtin_nontemporal_store(o1b, w2 + 1 * (HWHW / 2) + l + 128);
    __builtin_nontemporal_store(o2a, w2 + 2 * (HWHW / 2) + l);
    __builtin_nontemporal_store(o2b, w2 + 2 * (HWHW / 2) + l + 128);
    __builtin_nontemporal_store(o3a, w2 + 3 * (HWHW / 2) + l);
    __builtin_nontemporal_store(o3b, w2 + 3 * (HWHW / 2) + l + 128);
}

// ---------------------------------------------------------------------------
// Fallback (R0 path) if workspace is too small.
__global__ __launch_bounds__(256) void spatial_transform_chw(
    const float*  __restrict__ img,
    const float2* __restrict__ flow,
    float2*       __restrict__ grid_out,
    float*        __restrict__ warped)
{
    const int tid = blockIdx.x * blockDim.x + threadIdx.x;
    const int x = tid & (HW - 1);
    const int y = (tid >> 9) & (HW - 1);
    const int b = tid >> 18;

    const float2 f = flow[tid];
    const float scale = 2.0f / 511.0f;
    const float gy = fmaf((float)y, scale, -1.0f) + f.x;
    const float gx = fmaf((float)x, scale, -1.0f) + f.y;
    grid_out[tid] = make_float2(gx, gy);

    float xs = fminf(fmaxf((gx + 1.0f) * 0.5f * 511.0f, 0.0f), 511.0f);
    float ys = fminf(fmaxf((gy + 1.0f) * 0.5f * 511.0f, 0.0f), 511.0f);
    const float x0f = floorf(xs), y0f = floorf(ys);
    const float wx = xs - x0f, wy = ys - y0f;
    const int x0 = (int)x0f, y0 = (int)y0f;
    const int x1 = min(x0 + 1, HW - 1), y1 = min(y0 + 1, HW - 1);
    const float w00 = (1.0f - wx) * (1.0f - wy), w01 = wx * (1.0f - wy);
    const float w10 = (1.0f - wx) * wy,          w11 = wx * wy;
    const int o00 = y0 * HW + x0, o01 = y0 * HW + x1;
    const int o10 = y1 * HW + x0, o11 = y1 * HW + x1;
    const float* ib = img    + (size_t)b * CH * HWHW;
    float*       wb = warped + (size_t)b * CH * HWHW + y * HW + x;
#pragma unroll
    for (int c = 0; c < CH; ++c) {
        const float* pc = ib + c * HWHW;
        wb[c * HWHW] = pc[o00] * w00 + pc[o01] * w01 + pc[o10] * w10 + pc[o11] * w11;
    }
}

extern "C" void kernel_launch(void* const* d_in, const int* in_sizes, int n_in,
                              void* d_out, int out_size, void* d_ws, size_t ws_size,
                              hipStream_t stream) {
    const float* img  = (const float*)d_in[0];
    const void*  flow = d_in[1];

    float* grid_out = (float*)d_out;                                  // B*H*W*2 floats
    float* warped   = (float*)d_out + (size_t)BATCH * HWHW * 2;       // B*C*H*W floats

    const int n_px = BATCH * HWHW;                       // 4,194,304 pixels
    const size_t copy_bytes = (size_t)n_px * 8;          // 32 MiB per copy
    const size_t need = 2 * copy_bytes;                  // 64 MiB (E + O)

    if (ws_size >= need) {
        uint4* Ec = (uint4*)d_ws;
        uint4* Oc = (uint4*)((char*)d_ws + copy_bytes);
        transpose_fp16_dual<<<(n_px / 4) / 256, 256, 0, stream>>>(
            (const fvec4*)img, Ec, Oc);
        spatial_transform_fp16<<<(n_px / 4) / 256, 256, 0, stream>>>(
            (const uint4*)Ec, (const uint4*)Oc,
            (const fvec4*)flow, (fvec4*)grid_out, warped);
    } else {
        spatial_transform_chw<<<n_px / 256, 256, 0, stream>>>(
            img, (const float2*)flow, (float2*)grid_out, warped);
    }
}